// Round 18
// baseline (105.608 us; speedup 1.0000x reference)
//
#include <hip/hip_runtime.h>

#define J 17
#define F 128
#define TB 16

typedef __attribute__((ext_vector_type(4))) float f32x4;
typedef __attribute__((ext_vector_type(8))) short bf16x8;   // 8 bf16 in 4 VGPRs

__device__ __forceinline__ unsigned short f2bf(float f) {
    unsigned u = __builtin_bit_cast(unsigned, f);
    u += 0x7fffu + ((u >> 16) & 1u);
    return (unsigned short)(u >> 16);
}
__device__ __forceinline__ float bf2f(unsigned short s) {
    return __builtin_bit_cast(float, (unsigned)s << 16);
}
// pack two f32 (raw bits) -> two bf16, round-half-up: 2 v_add + 1 v_perm
__device__ __forceinline__ unsigned pkbf(unsigned lo, unsigned hi) {
    return __builtin_amdgcn_perm(hi + 0x8000u, lo + 0x8000u, 0x07060302u);
}
__device__ __forceinline__ f32x4 fma4(float a, f32x4 v, f32x4 c) {
    f32x4 av = {a, a, a, a};
    return __builtin_elementwise_fma(av, v, c);
}
__device__ __forceinline__ f32x4 bf4(ushort4 u) {
    return (f32x4){bf2f(u.x), bf2f(u.y), bf2f(u.z), bf2f(u.w)};
}
__device__ __forceinline__ f32x4 mfma16(bf16x8 a, bf16x8 b, f32x4 c) {
    return __builtin_amdgcn_mfma_f32_16x16x32_bf16(a, b, c, 0, 0, 0);
}
// async global->LDS DMA, 16B/lane; dest = wave-uniform base + lane*16 (HW rule)
__device__ __forceinline__ void dma16(const void* g, void* l) {
    __builtin_amdgcn_global_load_lds(
        (const __attribute__((address_space(1))) unsigned*)g,
        (__attribute__((address_space(3))) unsigned*)l, 16, 0, 0);
}

// ---- workspace layout (bytes) -------------------------------------------
//    0 : coefB f32[289] = A_off (diag zeroed)
// 1200 : flag  f32 at ws[300] = 1.0 iff max|A_off| < 1.25e-6
// 2048 : dMb  bf16[17*128] = Adiag[j]*M[j,g]            (full kernel, linear)
// 16384: WT   bf16[2][128][128], WT[mat][g][k] = bf16(W[mat][k][g])
// 81920: BLOB (37888 B, DMA'd whole into fast kernel's LDS):
//        +0     W0p  bf16[128*128] fragment order:
//               addr(g, o) = (g>>4)*4096 + ((o>>2))*1024 + (g&15)*64 + (o&3)*16
//        +32768 dM   j-swizzled: chunk c (16B) at (c*16)^(((c>>4)&7)<<4)
//        +37120 bias f32[128]
__global__ void prep(const float* __restrict__ W, const float* __restrict__ Mw,
                     const float* __restrict__ adj, const float* __restrict__ adj2,
                     const float* __restrict__ bias, float* __restrict__ ws) {
    unsigned short* WT  = (unsigned short*)((char*)ws + 16384);
    unsigned short* dMb = (unsigned short*)((char*)ws + 2048);
    unsigned char* blob = (unsigned char*)ws + 81920;
    int t = blockIdx.x * 256 + threadIdx.x;
    for (int idx = t; idx < 2 * F * F; idx += 16 * 256) {
        int mat = idx >> 14;
        int rem = idx & 16383;
        int g = rem >> 7, k = rem & 127;
        WT[idx] = f2bf(W[mat * 16384 + k * F + g]);
    }
    // W0 in fragment order (2048 16B chunks; c = g*16 + o)
    for (int c = t; c < 2048; c += 16 * 256) {
        int g = c >> 4, o = c & 15;
        unsigned short tmp[8];
#pragma unroll
        for (int e = 0; e < 8; ++e) tmp[e] = f2bf(W[(o * 8 + e) * F + g]);
        unsigned byte = (unsigned)(((g >> 4) << 12) + ((o >> 2) << 10)
                                 + ((g & 15) << 6) + ((o & 3) << 4));
        *(uint4*)(blob + byte) = *(const uint4*)tmp;
    }
    if (blockIdx.x == 0) {
        for (int idx = threadIdx.x; idx < J * J; idx += 256) {
            int i = idx / J, j = idx % J;
            float a = 0.5f * (adj[i*J+j] + adj2[i*J+j] + adj[j*J+i] + adj2[j*J+i]);
            ws[idx] = (i == j) ? 0.0f : a;
        }
        for (int idx = threadIdx.x; idx < J * F; idx += 256) {
            int j = idx >> 7;
            float adg = adj[j*J+j] + adj2[j*J+j];
            dMb[idx] = f2bf(adg * Mw[idx]);          // linear (full kernel)
        }
        // dM j-swizzled into blob (272 16B chunks)
        for (int c = threadIdx.x; c < 272; c += 256) {
            int j = c >> 4;
            float adg = adj[j*J+j] + adj2[j*J+j];
            unsigned short tmp[8];
#pragma unroll
            for (int e = 0; e < 8; ++e) tmp[e] = f2bf(adg * Mw[c * 8 + e]);
            unsigned byte = ((unsigned)c * 16u) ^ (((unsigned)(c >> 4) & 7u) << 4);
            *(uint4*)(blob + 32768 + byte) = *(const uint4*)tmp;
        }
        if (threadIdx.x < 32)
            ((uint4*)(blob + 37120))[threadIdx.x] = ((const uint4*)bias)[threadIdx.x];
        if (threadIdx.x < 64) {
            float mx = 0.0f;
            for (int idx = threadIdx.x; idx < J * J; idx += 64) {
                int i = idx / J, j = idx % J;
                if (i != j) {
                    float a = 0.5f * (adj[i*J+j] + adj2[i*J+j] + adj[j*J+i] + adj2[j*J+i]);
                    mx = fmaxf(mx, __builtin_fabsf(a));
                }
            }
#pragma unroll
            for (int o = 32; o; o >>= 1) mx = fmaxf(mx, __shfl_xor(mx, o, 64));
            if (threadIdx.x == 0) ws[300] = (mx < 1.25e-6f) ? 1.0f : 0.0f;
        }
    }
}

// ============ FAST kernel: flattened rows, barrier-free tile pipeline ========
// 278528 flat rows (b*17+j); tile = 16 consecutive rows; wave -> 4 tiles.
// LDS blob [W0p | dM_swz | bias] staged via global_load_lds (ZERO VGPRs).

__device__ __forceinline__ void loadtile(const float* __restrict__ x,
                                         int t, int lrow, int lq, uint4* q) {
    const uint4* p = (const uint4*)(x + (size_t)(t * 16 + lrow) * F) + lq * 2;
#pragma unroll
    for (int ks = 0; ks < 4; ++ks) { q[2*ks] = p[ks*8]; q[2*ks+1] = p[ks*8+1]; }
}
__device__ __forceinline__ void cvt_x(const uint4* q, bf16x8* xf) {
#pragma unroll
    for (int ks = 0; ks < 4; ++ks) {
        uint4 t;
        t.x = pkbf(q[2*ks].x,   q[2*ks].y);
        t.y = pkbf(q[2*ks].z,   q[2*ks].w);
        t.z = pkbf(q[2*ks+1].x, q[2*ks+1].y);
        t.w = pkbf(q[2*ks+1].z, q[2*ks+1].w);
        xf[ks] = __builtin_bit_cast(bf16x8, t);
    }
}

__device__ __forceinline__ void compute_tile(const unsigned char* Wl,
        const unsigned char* dMl, const float* biasl, float* __restrict__ out,
        int t, const bf16x8* xf, int lrow, int lq) {
    const unsigned flat = (unsigned)(t * 16 + lrow);
    const unsigned q17  = (unsigned)(((unsigned long long)flat * 0xF0F0F0F1ull) >> 36);
    const unsigned j    = flat - 17u * q17;
    float* orow = out + (size_t)flat * F;
    const unsigned loff = (unsigned)(lrow * 64 + lq * 16);   // fragment lane offset
    const unsigned dkey = (j & 7u) << 4;                      // dM j-swizzle
#pragma unroll
    for (int mt = 0; mt < 8; ++mt) {
        f32x4 h = {0.f, 0.f, 0.f, 0.f};
#pragma unroll
        for (int ks = 0; ks < 4; ++ks) {
            bf16x8 w = __builtin_bit_cast(bf16x8,
                *(const uint4*)(Wl + (unsigned)(mt * 4096 + ks * 1024) + loff));
            h = mfma16(w, xf[ks], h);
        }
        const int go = mt * 16 + lq * 4;
        f32x4 b4 = *(const f32x4*)(biasl + go);
        f32x4 d  = bf4(*(const ushort4*)(dMl + ((j * 256u + (unsigned)go * 2u) ^ dkey)));
        *(f32x4*)(orow + go) = __builtin_elementwise_fma(d, h, b4);
    }
}

__global__ __launch_bounds__(256, 2) void mgcn_fast(
    const float* __restrict__ x, const float* __restrict__ ws8,
    const float* __restrict__ ws, float* __restrict__ out) {
    if (ws[300] == 0.0f) return;    // off-diag significant -> full kernel handles

    __shared__ __align__(16) unsigned char smem[37888];   // [W0p|dM_swz|bias|pad]

    const int tid  = threadIdx.x;
    const int wv   = tid >> 6;
    const int lane = tid & 63;
    const int lrow = lane & 15;
    const int lq   = lane >> 4;
    const int t0   = (blockIdx.x * 4 + wv) * 4;   // 4 consecutive tiles per wave

    // issue first two tiles' x loads (VGPR) ...
    uint4 bufA[8], bufB[8];
    loadtile(x, t0 + 0, lrow, lq, bufA);
    loadtile(x, t0 + 1, lrow, lq, bufB);

    // ... then DMA the whole blob into LDS: zero VGPRs, overlaps with x loads.
    const unsigned char* blob = (const unsigned char*)ws + 81920;
    for (int g = wv; g < 37; g += 4)               // 37 groups x 1024B
        dma16(blob + g * 1024 + lane * 16, smem + g * 1024);
    __syncthreads();                                // drains DMA (vmcnt) + waves

    const unsigned char* Wl   = smem;
    const unsigned char* dMl  = smem + 32768;
    const float*         biasl = (const float*)(smem + 37120);

    // barrier-free pipeline: cvt frees buf -> reissue -> compute
    bf16x8 xf[4];
    cvt_x(bufA, xf);
    loadtile(x, t0 + 2, lrow, lq, bufA);
    compute_tile(Wl, dMl, biasl, out, t0 + 0, xf, lrow, lq);

    cvt_x(bufB, xf);
    loadtile(x, t0 + 3, lrow, lq, bufB);
    compute_tile(Wl, dMl, biasl, out, t0 + 1, xf, lrow, lq);

    cvt_x(bufA, xf);
    compute_tile(Wl, dMl, biasl, out, t0 + 2, xf, lrow, lq);

    cvt_x(bufB, xf);
    compute_tile(Wl, dMl, biasl, out, t0 + 3, xf, lrow, lq);
}

// ==================== FULL kernel: r10/r13 structure (passed) ================
__global__ __launch_bounds__(512, 2) void mgcn_full(
    const float* __restrict__ x, const float* __restrict__ Mw,
    const float* __restrict__ bias, const float* __restrict__ ws,
    float* __restrict__ out) {
    if (ws[300] != 0.0f) return;    // fast kernel handled it

    __shared__ __align__(16) unsigned char xs[TB * J * F * 2];   // 69632 B
    __shared__ __align__(16) unsigned short dMs[J * F];          //  4352 B

    const int tid  = threadIdx.x;
    const int b0   = blockIdx.x * TB;
    const int wave = tid >> 6;
    const int lane = tid & 63;
    const int lrow = lane & 15;
    const int lq   = lane >> 4;
    const int grow = wave * 16 + lrow;
    const int gq   = wave * 16 + lq * 4;
    const unsigned short* WT = (const unsigned short*)((const char*)ws + 16384);

    const float4* xg = (const float4*)(x + (size_t)b0 * (J * F));
    float4 s1[9], s2[8];
#pragma unroll
    for (int it = 0; it < 9; ++it) {
        int fi = it * 512 + tid;
        int b = fi / 288, r = fi - b * 288;
        s1[it] = xg[b * 544 + r];
    }
#pragma unroll
    for (int it = 0; it < 8; ++it) {
        int fi = it * 512 + tid;
        int b = fi >> 8, r = fi & 255;
        s2[it] = xg[b * 544 + 288 + r];
    }
    if (tid < 272)
        ((uint4*)dMs)[tid] = ((const uint4*)((const char*)ws + 2048))[tid];

    const f32x4 bias4 = *(const f32x4*)(bias + gq);

#pragma unroll
    for (int it = 0; it < 9; ++it) {
        int fi = it * 512 + tid;
        int b = fi / 288, r = fi - b * 288;
        int j = r >> 5, k4 = r & 31;
        unsigned byte = (unsigned)(b * 4352 + j * 256 + k4 * 8)
                      ^ (unsigned)((b & 7) << 4);
        uint4 u = __builtin_bit_cast(uint4, s1[it]);
        uint2 p; p.x = pkbf(u.x, u.y); p.y = pkbf(u.z, u.w);
        *(uint2*)(xs + byte) = p;
    }
#pragma unroll
    for (int it = 0; it < 8; ++it) {
        int fi = it * 512 + tid;
        int b = fi >> 8, r = fi & 255;
        int j = 9 + (r >> 5), k4 = r & 31;
        unsigned byte = (unsigned)(b * 4352 + j * 256 + k4 * 8)
                      ^ (unsigned)((b & 7) << 4);
        uint4 u = __builtin_bit_cast(uint4, s2[it]);
        uint2 p; p.x = pkbf(u.x, u.y); p.y = pkbf(u.z, u.w);
        *(uint2*)(xs + byte) = p;
    }
    __syncthreads();

    const unsigned rbase = (unsigned)(lrow * 4352);
    const unsigned swz   = (unsigned)((lrow & 7) << 4);
    float* ob = out + ((size_t)(b0 + lrow) * J) * F + gq;

    f32x4 acc[J];
#pragma unroll
    for (int i = 0; i < J; ++i) acc[i] = bias4;

    {   // pass B: off-diagonal (wf1 only live)
        bf16x8 wf[4];
#pragma unroll
        for (int ks = 0; ks < 4; ++ks)
            wf[ks] = __builtin_bit_cast(bf16x8,
                *(const uint4*)(WT + (size_t)(F * F) + (size_t)grow * F + ks * 32 + lq * 8));
#pragma unroll
        for (int j = 0; j < J; ++j) {
            f32x4 h1 = {0.f,0.f,0.f,0.f};
#pragma unroll
            for (int ks = 0; ks < 4; ++ks) {
                unsigned byte = (rbase + (unsigned)(j * 256 + ks * 64 + lq * 16)) ^ swz;
                bf16x8 xf = __builtin_bit_cast(bf16x8, *(const uint4*)(xs + byte));
                h1 = __builtin_amdgcn_mfma_f32_16x16x32_bf16(wf[ks], xf, h1, 0, 0, 0);
            }
            f32x4 mj  = *(const f32x4*)&Mw[j * F + gq];
            f32x4 mh1 = mj * h1;
#pragma unroll
            for (int i = 0; i < J; ++i)
                acc[i] = fma4(ws[i * J + j], mh1, acc[i]);
        }
    }
    {   // pass A: diagonal (wf0 only live)
        bf16x8 wf[4];
#pragma unroll
        for (int ks = 0; ks < 4; ++ks)
            wf[ks] = __builtin_bit_cast(bf16x8,
                *(const uint4*)(WT + (size_t)grow * F + ks * 32 + lq * 8));
#pragma unroll
        for (int j = 0; j < J; ++j) {
            f32x4 h0 = {0.f,0.f,0.f,0.f};
#pragma unroll
            for (int ks = 0; ks < 4; ++ks) {
                unsigned byte = (rbase + (unsigned)(j * 256 + ks * 64 + lq * 16)) ^ swz;
                bf16x8 xf = __builtin_bit_cast(bf16x8, *(const uint4*)(xs + byte));
                h0 = __builtin_amdgcn_mfma_f32_16x16x32_bf16(wf[ks], xf, h0, 0, 0, 0);
            }
            f32x4 dj = bf4(*(const ushort4*)(dMs + j * F + gq));
            acc[j] = __builtin_elementwise_fma(dj, h0, acc[j]);
            *(f32x4*)(ob + (size_t)j * F) = acc[j];
        }
    }
}

extern "C" void kernel_launch(void* const* d_in, const int* in_sizes, int n_in,
                              void* d_out, int out_size, void* d_ws, size_t ws_size,
                              hipStream_t stream) {
    const float* x    = (const float*)d_in[0];
    const float* W    = (const float*)d_in[1];
    const float* Mw   = (const float*)d_in[2];
    const float* adj  = (const float*)d_in[3];
    const float* adj2 = (const float*)d_in[4];
    const float* bias = (const float*)d_in[5];
    float* out = (float*)d_out;
    float* ws  = (float*)d_ws;   // needs >= 119808 B

    int Btot = in_sizes[0] / (J * F);        // 16384
    int tiles = Btot * J / 16;               // 17408 flat row-tiles
    prep<<<16, 256, 0, stream>>>(W, Mw, adj, adj2, bias, ws);
    mgcn_fast<<<tiles / 16, 256, 0, stream>>>(x, ws, ws, out);    // 1088 blocks
    mgcn_full<<<Btot / TB, 512, 0, stream>>>(x, Mw, bias, ws, out);
}

// Round 19
// 83.913 us; speedup vs baseline: 1.2585x; 1.2585x over previous
//
#include <hip/hip_runtime.h>

#define J 17
#define F 128
#define TB 16

typedef __attribute__((ext_vector_type(4))) float f32x4;
typedef __attribute__((ext_vector_type(8))) short bf16x8;   // 8 bf16 in 4 VGPRs

__device__ __forceinline__ unsigned short f2bf(float f) {
    unsigned u = __builtin_bit_cast(unsigned, f);
    u += 0x7fffu + ((u >> 16) & 1u);
    return (unsigned short)(u >> 16);
}
__device__ __forceinline__ float bf2f(unsigned short s) {
    return __builtin_bit_cast(float, (unsigned)s << 16);
}
// pack two f32 (raw bits) -> two bf16, round-half-up: 2 v_add + 1 v_perm
__device__ __forceinline__ unsigned pkbf(unsigned lo, unsigned hi) {
    return __builtin_amdgcn_perm(hi + 0x8000u, lo + 0x8000u, 0x07060302u);
}
__device__ __forceinline__ f32x4 fma4(float a, f32x4 v, f32x4 c) {
    f32x4 av = {a, a, a, a};
    return __builtin_elementwise_fma(av, v, c);
}
__device__ __forceinline__ f32x4 bf4(ushort4 u) {
    return (f32x4){bf2f(u.x), bf2f(u.y), bf2f(u.z), bf2f(u.w)};
}
__device__ __forceinline__ f32x4 mfma16(bf16x8 a, bf16x8 b, f32x4 c) {
    return __builtin_amdgcn_mfma_f32_16x16x32_bf16(a, b, c, 0, 0, 0);
}
// async global->LDS DMA, 16B/lane; dest = wave-uniform base (+ lane*16 by HW)
__device__ __forceinline__ void dma16(const void* g, void* l) {
    __builtin_amdgcn_global_load_lds(
        (const __attribute__((address_space(1))) unsigned*)g,
        (__attribute__((address_space(3))) unsigned*)l, 16, 0, 0);
}

// ---- workspace layout (bytes) -------------------------------------------
//    0 : coefB f32[289] = A_off (diag zeroed)
// 1200 : flag  f32 at ws[300] = 1.0 iff max|A_off| < 1.25e-6
// 2048 : dMb  bf16[17*128] = Adiag[j]*M[j,g]            (full kernel)
// 16384: WT   bf16[2][128][128], WT[mat][g][k] = bf16(W[mat][k][g])
// 81920: BLOB (37888 B, DMA'd whole into fast kernel's LDS):
//        +0     W0p  bf16[128*128] fragment order:
//               addr(g, o) = (g>>4)*4096 + (o>>2)*1024 + (g&15)*64 + (o&3)*16
//        +32768 dM   bf16[17*128] LINEAR
//        +37120 bias f32[128]
__global__ void prep(const float* __restrict__ W, const float* __restrict__ Mw,
                     const float* __restrict__ adj, const float* __restrict__ adj2,
                     const float* __restrict__ bias, float* __restrict__ ws) {
    unsigned short* WT  = (unsigned short*)((char*)ws + 16384);
    unsigned short* dMb = (unsigned short*)((char*)ws + 2048);
    unsigned char* blob = (unsigned char*)ws + 81920;
    int t = blockIdx.x * 256 + threadIdx.x;
    for (int idx = t; idx < 2 * F * F; idx += 16 * 256) {
        int mat = idx >> 14;
        int rem = idx & 16383;
        int g = rem >> 7, k = rem & 127;
        WT[idx] = f2bf(W[mat * 16384 + k * F + g]);
    }
    // W0 in fragment order (2048 16B chunks; c = g*16 + o)
    for (int c = t; c < 2048; c += 16 * 256) {
        int g = c >> 4, o = c & 15;
        unsigned short tmp[8];
#pragma unroll
        for (int e = 0; e < 8; ++e) tmp[e] = f2bf(W[(o * 8 + e) * F + g]);
        unsigned byte = (unsigned)(((g >> 4) << 12) + ((o >> 2) << 10)
                                 + ((g & 15) << 6) + ((o & 3) << 4));
        *(uint4*)(blob + byte) = *(const uint4*)tmp;
    }
    if (blockIdx.x == 0) {
        for (int idx = threadIdx.x; idx < J * J; idx += 256) {
            int i = idx / J, j = idx % J;
            float a = 0.5f * (adj[i*J+j] + adj2[i*J+j] + adj[j*J+i] + adj2[j*J+i]);
            ws[idx] = (i == j) ? 0.0f : a;
        }
        for (int idx = threadIdx.x; idx < J * F; idx += 256) {
            int j = idx >> 7;
            float adg = adj[j*J+j] + adj2[j*J+j];
            dMb[idx] = f2bf(adg * Mw[idx]);          // full kernel copy
        }
        // dM LINEAR into blob (272 16B chunks)
        for (int c = threadIdx.x; c < 272; c += 256) {
            int j = c >> 4;
            float adg = adj[j*J+j] + adj2[j*J+j];
            unsigned short tmp[8];
#pragma unroll
            for (int e = 0; e < 8; ++e) tmp[e] = f2bf(adg * Mw[c * 8 + e]);
            *(uint4*)(blob + 32768 + c * 16) = *(const uint4*)tmp;
        }
        if (threadIdx.x < 32)
            ((uint4*)(blob + 37120))[threadIdx.x] = ((const uint4*)bias)[threadIdx.x];
        if (threadIdx.x < 64) {
            float mx = 0.0f;
            for (int idx = threadIdx.x; idx < J * J; idx += 64) {
                int i = idx / J, j = idx % J;
                if (i != j) {
                    float a = 0.5f * (adj[i*J+j] + adj2[i*J+j] + adj[j*J+i] + adj2[j*J+i]);
                    mx = fmaxf(mx, __builtin_fabsf(a));
                }
            }
#pragma unroll
            for (int o = 32; o; o >>= 1) mx = fmaxf(mx, __shfl_xor(mx, o, 64));
            if (threadIdx.x == 0) ws[300] = (mx < 1.25e-6f) ? 1.0f : 0.0f;
        }
    }
}

// ============ FAST kernel: flattened rows, barrier-free tile pipeline ========
// 278528 flat rows (b*17+j); tile = 16 consecutive rows; wave -> 4 tiles.
// LDS blob [W0p | dM | bias] staged via global_load_lds (ZERO VGPRs).
// mt loop is unroll(1): caps live W-fragments at 4 (16 VGPRs) -> no spill.

__device__ __forceinline__ void loadtile(const float* __restrict__ x,
                                         int t, int lrow, int lq, uint4* q) {
    const uint4* p = (const uint4*)(x + (size_t)(t * 16 + lrow) * F) + lq * 2;
#pragma unroll
    for (int ks = 0; ks < 4; ++ks) { q[2*ks] = p[ks*8]; q[2*ks+1] = p[ks*8+1]; }
}
__device__ __forceinline__ void cvt_x(const uint4* q, bf16x8* xf) {
#pragma unroll
    for (int ks = 0; ks < 4; ++ks) {
        uint4 t;
        t.x = pkbf(q[2*ks].x,   q[2*ks].y);
        t.y = pkbf(q[2*ks].z,   q[2*ks].w);
        t.z = pkbf(q[2*ks+1].x, q[2*ks+1].y);
        t.w = pkbf(q[2*ks+1].z, q[2*ks+1].w);
        xf[ks] = __builtin_bit_cast(bf16x8, t);
    }
}

__device__ __forceinline__ void compute_tile(const unsigned char* Wl,
        const unsigned char* dMl, const float* biasl, float* __restrict__ out,
        int t, const bf16x8* xf, int lrow, int lq) {
    const unsigned flat = (unsigned)(t * 16 + lrow);
    const unsigned q17  = (unsigned)(((unsigned long long)flat * 0xF0F0F0F1ull) >> 36);
    const unsigned j    = flat - 17u * q17;
    float* orow = out + (size_t)flat * F;
    const unsigned loff = (unsigned)(lrow * 64 + lq * 16);   // fragment lane offset
#pragma unroll 1   // KEY: keep ds_read batching within one mt (4 live W-frags max)
    for (int mt = 0; mt < 8; ++mt) {
        const unsigned char* wp = Wl + (unsigned)(mt * 4096) + loff;
        f32x4 h = {0.f, 0.f, 0.f, 0.f};
#pragma unroll
        for (int ks = 0; ks < 4; ++ks) {
            bf16x8 w = __builtin_bit_cast(bf16x8, *(const uint4*)(wp + ks * 1024));
            h = mfma16(w, xf[ks], h);
        }
        const int go = mt * 16 + lq * 4;
        f32x4 b4 = *(const f32x4*)(biasl + go);
        f32x4 d  = bf4(*(const ushort4*)(dMl + (unsigned)(j * 256 + go * 2)));
        *(f32x4*)(orow + go) = __builtin_elementwise_fma(d, h, b4);
    }
}

__global__ __launch_bounds__(256, 2) void mgcn_fast(
    const float* __restrict__ x, const float* __restrict__ ws8,
    const float* __restrict__ ws, float* __restrict__ out) {
    if (ws[300] == 0.0f) return;    // off-diag significant -> full kernel handles

    __shared__ __align__(16) unsigned char smem[37888];   // [W0p|dM|bias|pad]

    const int tid  = threadIdx.x;
    const int wv   = tid >> 6;
    const int lane = tid & 63;
    const int lrow = lane & 15;
    const int lq   = lane >> 4;
    const int t0   = (blockIdx.x * 4 + wv) * 4;   // 4 consecutive tiles per wave

    // issue first two tiles' x loads (VGPR) ...
    uint4 bufA[8], bufB[8];
    loadtile(x, t0 + 0, lrow, lq, bufA);
    loadtile(x, t0 + 1, lrow, lq, bufB);

    // ... then DMA the whole blob into LDS: zero VGPRs, overlaps with x loads.
    const unsigned char* blob = (const unsigned char*)ws + 81920;
    for (int g = wv; g < 37; g += 4)               // 37 groups x 1024B
        dma16(blob + g * 1024 + lane * 16, smem + g * 1024);
    __syncthreads();                                // drains DMA (vmcnt) + waves

    const unsigned char* Wl    = smem;
    const unsigned char* dMl   = smem + 32768;
    const float*         biasl = (const float*)(smem + 37120);

    // barrier-free pipeline: cvt frees buf -> reissue -> compute
    bf16x8 xf[4];
    cvt_x(bufA, xf);
    loadtile(x, t0 + 2, lrow, lq, bufA);
    compute_tile(Wl, dMl, biasl, out, t0 + 0, xf, lrow, lq);

    cvt_x(bufB, xf);
    loadtile(x, t0 + 3, lrow, lq, bufB);
    compute_tile(Wl, dMl, biasl, out, t0 + 1, xf, lrow, lq);

    cvt_x(bufA, xf);
    compute_tile(Wl, dMl, biasl, out, t0 + 2, xf, lrow, lq);

    cvt_x(bufB, xf);
    compute_tile(Wl, dMl, biasl, out, t0 + 3, xf, lrow, lq);
}

// ==================== FULL kernel: r10/r13 structure (passed) ================
__global__ __launch_bounds__(512, 2) void mgcn_full(
    const float* __restrict__ x, const float* __restrict__ Mw,
    const float* __restrict__ bias, const float* __restrict__ ws,
    float* __restrict__ out) {
    if (ws[300] != 0.0f) return;    // fast kernel handled it

    __shared__ __align__(16) unsigned char xs[TB * J * F * 2];   // 69632 B
    __shared__ __align__(16) unsigned short dMs[J * F];          //  4352 B

    const int tid  = threadIdx.x;
    const int b0   = blockIdx.x * TB;
    const int wave = tid >> 6;
    const int lane = tid & 63;
    const int lrow = lane & 15;
    const int lq   = lane >> 4;
    const int grow = wave * 16 + lrow;
    const int gq   = wave * 16 + lq * 4;
    const unsigned short* WT = (const unsigned short*)((const char*)ws + 16384);

    const float4* xg = (const float4*)(x + (size_t)b0 * (J * F));
    float4 s1[9], s2[8];
#pragma unroll
    for (int it = 0; it < 9; ++it) {
        int fi = it * 512 + tid;
        int b = fi / 288, r = fi - b * 288;
        s1[it] = xg[b * 544 + r];
    }
#pragma unroll
    for (int it = 0; it < 8; ++it) {
        int fi = it * 512 + tid;
        int b = fi >> 8, r = fi & 255;
        s2[it] = xg[b * 544 + 288 + r];
    }
    if (tid < 272)
        ((uint4*)dMs)[tid] = ((const uint4*)((const char*)ws + 2048))[tid];

    const f32x4 bias4 = *(const f32x4*)(bias + gq);

#pragma unroll
    for (int it = 0; it < 9; ++it) {
        int fi = it * 512 + tid;
        int b = fi / 288, r = fi - b * 288;
        int j = r >> 5, k4 = r & 31;
        unsigned byte = (unsigned)(b * 4352 + j * 256 + k4 * 8)
                      ^ (unsigned)((b & 7) << 4);
        uint4 u = __builtin_bit_cast(uint4, s1[it]);
        uint2 p; p.x = pkbf(u.x, u.y); p.y = pkbf(u.z, u.w);
        *(uint2*)(xs + byte) = p;
    }
#pragma unroll
    for (int it = 0; it < 8; ++it) {
        int fi = it * 512 + tid;
        int b = fi >> 8, r = fi & 255;
        int j = 9 + (r >> 5), k4 = r & 31;
        unsigned byte = (unsigned)(b * 4352 + j * 256 + k4 * 8)
                      ^ (unsigned)((b & 7) << 4);
        uint4 u = __builtin_bit_cast(uint4, s2[it]);
        uint2 p; p.x = pkbf(u.x, u.y); p.y = pkbf(u.z, u.w);
        *(uint2*)(xs + byte) = p;
    }
    __syncthreads();

    const unsigned rbase = (unsigned)(lrow * 4352);
    const unsigned swz   = (unsigned)((lrow & 7) << 4);
    float* ob = out + ((size_t)(b0 + lrow) * J) * F + gq;

    f32x4 acc[J];
#pragma unroll
    for (int i = 0; i < J; ++i) acc[i] = bias4;

    {   // pass B: off-diagonal (wf1 only live)
        bf16x8 wf[4];
#pragma unroll
        for (int ks = 0; ks < 4; ++ks)
            wf[ks] = __builtin_bit_cast(bf16x8,
                *(const uint4*)(WT + (size_t)(F * F) + (size_t)grow * F + ks * 32 + lq * 8));
#pragma unroll
        for (int j = 0; j < J; ++j) {
            f32x4 h1 = {0.f,0.f,0.f,0.f};
#pragma unroll
            for (int ks = 0; ks < 4; ++ks) {
                unsigned byte = (rbase + (unsigned)(j * 256 + ks * 64 + lq * 16)) ^ swz;
                bf16x8 xf = __builtin_bit_cast(bf16x8, *(const uint4*)(xs + byte));
                h1 = __builtin_amdgcn_mfma_f32_16x16x32_bf16(wf[ks], xf, h1, 0, 0, 0);
            }
            f32x4 mj  = *(const f32x4*)&Mw[j * F + gq];
            f32x4 mh1 = mj * h1;
#pragma unroll
            for (int i = 0; i < J; ++i)
                acc[i] = fma4(ws[i * J + j], mh1, acc[i]);
        }
    }
    {   // pass A: diagonal (wf0 only live)
        bf16x8 wf[4];
#pragma unroll
        for (int ks = 0; ks < 4; ++ks)
            wf[ks] = __builtin_bit_cast(bf16x8,
                *(const uint4*)(WT + (size_t)grow * F + ks * 32 + lq * 8));
#pragma unroll
        for (int j = 0; j < J; ++j) {
            f32x4 h0 = {0.f,0.f,0.f,0.f};
#pragma unroll
            for (int ks = 0; ks < 4; ++ks) {
                unsigned byte = (rbase + (unsigned)(j * 256 + ks * 64 + lq * 16)) ^ swz;
                bf16x8 xf = __builtin_bit_cast(bf16x8, *(const uint4*)(xs + byte));
                h0 = __builtin_amdgcn_mfma_f32_16x16x32_bf16(wf[ks], xf, h0, 0, 0, 0);
            }
            f32x4 dj = bf4(*(const ushort4*)(dMs + j * F + gq));
            acc[j] = __builtin_elementwise_fma(dj, h0, acc[j]);
            *(f32x4*)(ob + (size_t)j * F) = acc[j];
        }
    }
}

extern "C" void kernel_launch(void* const* d_in, const int* in_sizes, int n_in,
                              void* d_out, int out_size, void* d_ws, size_t ws_size,
                              hipStream_t stream) {
    const float* x    = (const float*)d_in[0];
    const float* W    = (const float*)d_in[1];
    const float* Mw   = (const float*)d_in[2];
    const float* adj  = (const float*)d_in[3];
    const float* adj2 = (const float*)d_in[4];
    const float* bias = (const float*)d_in[5];
    float* out = (float*)d_out;
    float* ws  = (float*)d_ws;   // needs >= 119808 B

    int Btot = in_sizes[0] / (J * F);        // 16384
    int tiles = Btot * J / 16;               // 17408 flat row-tiles
    prep<<<16, 256, 0, stream>>>(W, Mw, adj, adj2, bias, ws);
    mgcn_fast<<<tiles / 16, 256, 0, stream>>>(x, ws, ws, out);    // 1088 blocks
    mgcn_full<<<Btot / TB, 512, 0, stream>>>(x, Mw, bias, ws, out);
}

// Round 20
// 83.544 us; speedup vs baseline: 1.2641x; 1.0044x over previous
//
#include <hip/hip_runtime.h>

#define J 17
#define F 128
#define TB 16

typedef __attribute__((ext_vector_type(4))) float f32x4;
typedef __attribute__((ext_vector_type(8))) short bf16x8;   // 8 bf16 in 4 VGPRs

__device__ __forceinline__ unsigned short f2bf(float f) {
    unsigned u = __builtin_bit_cast(unsigned, f);
    u += 0x7fffu + ((u >> 16) & 1u);
    return (unsigned short)(u >> 16);
}
__device__ __forceinline__ float bf2f(unsigned short s) {
    return __builtin_bit_cast(float, (unsigned)s << 16);
}
// pack two f32 (raw bits) -> two bf16, round-half-up: 2 v_add + 1 v_perm
__device__ __forceinline__ unsigned pkbf(unsigned lo, unsigned hi) {
    return __builtin_amdgcn_perm(hi + 0x8000u, lo + 0x8000u, 0x07060302u);
}
__device__ __forceinline__ f32x4 fma4(float a, f32x4 v, f32x4 c) {
    f32x4 av = {a, a, a, a};
    return __builtin_elementwise_fma(av, v, c);
}
__device__ __forceinline__ f32x4 bf4(ushort4 u) {
    return (f32x4){bf2f(u.x), bf2f(u.y), bf2f(u.z), bf2f(u.w)};
}
__device__ __forceinline__ f32x4 mfma16(bf16x8 a, bf16x8 b, f32x4 c) {
    return __builtin_amdgcn_mfma_f32_16x16x32_bf16(a, b, c, 0, 0, 0);
}
// async global->LDS DMA, 16B/lane; dest = wave-uniform base (+ lane*16 by HW)
__device__ __forceinline__ void dma16(const void* g, void* l) {
    __builtin_amdgcn_global_load_lds(
        (const __attribute__((address_space(1))) unsigned*)g,
        (__attribute__((address_space(3))) unsigned*)l, 16, 0, 0);
}

// ---- workspace layout (bytes) -------------------------------------------
//    0 : coefB f32[289] = A_off (diag zeroed)
// 1200 : flag  f32 at ws[300] = 1.0 iff max|A_off| < 1.25e-6
// 2048 : dMb  bf16[17*128] = Adiag[j]*M[j,g]            (full kernel)
// 16384: WT   bf16[2][128][128], WT[mat][g][k] = bf16(W[mat][k][g])
// 81920: BLOB (37888 B, DMA'd whole into fast kernel's LDS):
//        +0     W0p  bf16[128*128] fragment order:
//               addr(g, o) = (g>>4)*4096 + (o>>2)*1024 + (g&15)*64 + (o&3)*16
//        +32768 dM   j-swizzled: chunk c (16B) at (c*16)^(((c>>4)&7)<<4)
//        +37120 bias f32[128]
__global__ void prep(const float* __restrict__ W, const float* __restrict__ Mw,
                     const float* __restrict__ adj, const float* __restrict__ adj2,
                     const float* __restrict__ bias, float* __restrict__ ws) {
    unsigned short* WT  = (unsigned short*)((char*)ws + 16384);
    unsigned short* dMb = (unsigned short*)((char*)ws + 2048);
    unsigned char* blob = (unsigned char*)ws + 81920;
    int t = blockIdx.x * 256 + threadIdx.x;
    for (int idx = t; idx < 2 * F * F; idx += 16 * 256) {
        int mat = idx >> 14;
        int rem = idx & 16383;
        int g = rem >> 7, k = rem & 127;
        WT[idx] = f2bf(W[mat * 16384 + k * F + g]);
    }
    // W0 in fragment order (2048 16B chunks; c = g*16 + o)
    for (int c = t; c < 2048; c += 16 * 256) {
        int g = c >> 4, o = c & 15;
        unsigned short tmp[8];
#pragma unroll
        for (int e = 0; e < 8; ++e) tmp[e] = f2bf(W[(o * 8 + e) * F + g]);
        unsigned byte = (unsigned)(((g >> 4) << 12) + ((o >> 2) << 10)
                                 + ((g & 15) << 6) + ((o & 3) << 4));
        *(uint4*)(blob + byte) = *(const uint4*)tmp;
    }
    if (blockIdx.x == 0) {
        for (int idx = threadIdx.x; idx < J * J; idx += 256) {
            int i = idx / J, j = idx % J;
            float a = 0.5f * (adj[i*J+j] + adj2[i*J+j] + adj[j*J+i] + adj2[j*J+i]);
            ws[idx] = (i == j) ? 0.0f : a;
        }
        for (int idx = threadIdx.x; idx < J * F; idx += 256) {
            int j = idx >> 7;
            float adg = adj[j*J+j] + adj2[j*J+j];
            dMb[idx] = f2bf(adg * Mw[idx]);          // full kernel copy
        }
        // dM j-swizzled into blob (272 16B chunks) — kills stride-256B conflicts
        for (int c = threadIdx.x; c < 272; c += 256) {
            int j = c >> 4;
            float adg = adj[j*J+j] + adj2[j*J+j];
            unsigned short tmp[8];
#pragma unroll
            for (int e = 0; e < 8; ++e) tmp[e] = f2bf(adg * Mw[c * 8 + e]);
            unsigned byte = ((unsigned)c * 16u) ^ (((unsigned)(c >> 4) & 7u) << 4);
            *(uint4*)(blob + 32768 + byte) = *(const uint4*)tmp;
        }
        if (threadIdx.x < 32)
            ((uint4*)(blob + 37120))[threadIdx.x] = ((const uint4*)bias)[threadIdx.x];
        if (threadIdx.x < 64) {
            float mx = 0.0f;
            for (int idx = threadIdx.x; idx < J * J; idx += 64) {
                int i = idx / J, j = idx % J;
                if (i != j) {
                    float a = 0.5f * (adj[i*J+j] + adj2[i*J+j] + adj[j*J+i] + adj2[j*J+i]);
                    mx = fmaxf(mx, __builtin_fabsf(a));
                }
            }
#pragma unroll
            for (int o = 32; o; o >>= 1) mx = fmaxf(mx, __shfl_xor(mx, o, 64));
            if (threadIdx.x == 0) ws[300] = (mx < 1.25e-6f) ? 1.0f : 0.0f;
        }
    }
}

// ============ FAST kernel: flattened rows, pinned-issue tile pipeline ========
// 278528 flat rows (b*17+j); tile = 16 consecutive rows; wave -> 4 tiles.
// LDS blob [W0p | dM_swz | bias] via global_load_lds (zero staging VGPRs).
// sched_barrier(0) after each loadtile pins the prefetch ABOVE the compute:
// without it the scheduler sinks loads to their use (r19: VGPR=60, serial).

__device__ __forceinline__ void loadtile(const float* __restrict__ x,
                                         int t, int lrow, int lq, uint4* q) {
    const uint4* p = (const uint4*)(x + (size_t)(t * 16 + lrow) * F) + lq * 2;
#pragma unroll
    for (int ks = 0; ks < 4; ++ks) { q[2*ks] = p[ks*8]; q[2*ks+1] = p[ks*8+1]; }
}
__device__ __forceinline__ void cvt_x(const uint4* q, bf16x8* xf) {
#pragma unroll
    for (int ks = 0; ks < 4; ++ks) {
        uint4 t;
        t.x = pkbf(q[2*ks].x,   q[2*ks].y);
        t.y = pkbf(q[2*ks].z,   q[2*ks].w);
        t.z = pkbf(q[2*ks+1].x, q[2*ks+1].y);
        t.w = pkbf(q[2*ks+1].z, q[2*ks+1].w);
        xf[ks] = __builtin_bit_cast(bf16x8, t);
    }
}

__device__ __forceinline__ void compute_tile(const unsigned char* Wl,
        const unsigned char* dMl, const float* biasl, float* __restrict__ out,
        int t, const bf16x8* xf, int lrow, int lq) {
    const unsigned flat = (unsigned)(t * 16 + lrow);
    const unsigned q17  = (unsigned)(((unsigned long long)flat * 0xF0F0F0F1ull) >> 36);
    const unsigned j    = flat - 17u * q17;
    float* orow = out + (size_t)flat * F;
    const unsigned loff = (unsigned)(lrow * 64 + lq * 16);   // fragment lane offset
    const unsigned dkey = (j & 7u) << 4;                      // dM j-swizzle
#pragma unroll 1   // cap live W-fragments at 4 (16 VGPRs) -> no spill (r19)
    for (int mt = 0; mt < 8; ++mt) {
        const unsigned char* wp = Wl + (unsigned)(mt * 4096) + loff;
        f32x4 h = {0.f, 0.f, 0.f, 0.f};
#pragma unroll
        for (int ks = 0; ks < 4; ++ks) {
            bf16x8 w = __builtin_bit_cast(bf16x8, *(const uint4*)(wp + ks * 1024));
            h = mfma16(w, xf[ks], h);
        }
        const int go = mt * 16 + lq * 4;
        f32x4 b4 = *(const f32x4*)(biasl + go);
        f32x4 d  = bf4(*(const ushort4*)(dMl + ((j * 256u + (unsigned)go * 2u) ^ dkey)));
        *(f32x4*)(orow + go) = __builtin_elementwise_fma(d, h, b4);
    }
}

__global__ __launch_bounds__(256, 2) void mgcn_fast(
    const float* __restrict__ x, const float* __restrict__ ws8,
    const float* __restrict__ ws, float* __restrict__ out) {
    if (ws[300] == 0.0f) return;    // off-diag significant -> full kernel handles

    __shared__ __align__(16) unsigned char smem[37888];   // [W0p|dM_swz|bias|pad]

    const int tid  = threadIdx.x;
    const int wv   = tid >> 6;
    const int lane = tid & 63;
    const int lrow = lane & 15;
    const int lq   = lane >> 4;
    const int t0   = (blockIdx.x * 4 + wv) * 4;   // 4 consecutive tiles per wave

    // issue first two tiles' x loads (VGPR), PINNED above everything below
    uint4 bufA[8], bufB[8];
    loadtile(x, t0 + 0, lrow, lq, bufA);
    loadtile(x, t0 + 1, lrow, lq, bufB);
    __builtin_amdgcn_sched_barrier(0);

    // DMA the whole blob into LDS: zero VGPRs, overlaps with the x loads
    const unsigned char* blob = (const unsigned char*)ws + 81920;
    for (int g = wv; g < 37; g += 4)               // 37 groups x 1024B
        dma16(blob + g * 1024 + lane * 16, smem + g * 1024);
    __syncthreads();                                // drains DMA (vmcnt) + waves

    const unsigned char* Wl    = smem;
    const unsigned char* dMl   = smem + 32768;
    const float*         biasl = (const float*)(smem + 37120);

    // pinned-issue pipeline: prefetch t+2 is guaranteed in flight during compute
    bf16x8 xf[4];
    cvt_x(bufA, xf);
    loadtile(x, t0 + 2, lrow, lq, bufA);
    __builtin_amdgcn_sched_barrier(0);
    compute_tile(Wl, dMl, biasl, out, t0 + 0, xf, lrow, lq);

    cvt_x(bufB, xf);
    loadtile(x, t0 + 3, lrow, lq, bufB);
    __builtin_amdgcn_sched_barrier(0);
    compute_tile(Wl, dMl, biasl, out, t0 + 1, xf, lrow, lq);

    cvt_x(bufA, xf);
    compute_tile(Wl, dMl, biasl, out, t0 + 2, xf, lrow, lq);

    cvt_x(bufB, xf);
    compute_tile(Wl, dMl, biasl, out, t0 + 3, xf, lrow, lq);
}

// ==================== FULL kernel: r10/r13 structure (passed) ================
__global__ __launch_bounds__(512, 2) void mgcn_full(
    const float* __restrict__ x, const float* __restrict__ Mw,
    const float* __restrict__ bias, const float* __restrict__ ws,
    float* __restrict__ out) {
    if (ws[300] != 0.0f) return;    // fast kernel handled it

    __shared__ __align__(16) unsigned char xs[TB * J * F * 2];   // 69632 B
    __shared__ __align__(16) unsigned short dMs[J * F];          //  4352 B

    const int tid  = threadIdx.x;
    const int b0   = blockIdx.x * TB;
    const int wave = tid >> 6;
    const int lane = tid & 63;
    const int lrow = lane & 15;
    const int lq   = lane >> 4;
    const int grow = wave * 16 + lrow;
    const int gq   = wave * 16 + lq * 4;
    const unsigned short* WT = (const unsigned short*)((const char*)ws + 16384);

    const float4* xg = (const float4*)(x + (size_t)b0 * (J * F));
    float4 s1[9], s2[8];
#pragma unroll
    for (int it = 0; it < 9; ++it) {
        int fi = it * 512 + tid;
        int b = fi / 288, r = fi - b * 288;
        s1[it] = xg[b * 544 + r];
    }
#pragma unroll
    for (int it = 0; it < 8; ++it) {
        int fi = it * 512 + tid;
        int b = fi >> 8, r = fi & 255;
        s2[it] = xg[b * 544 + 288 + r];
    }
    if (tid < 272)
        ((uint4*)dMs)[tid] = ((const uint4*)((const char*)ws + 2048))[tid];

    const f32x4 bias4 = *(const f32x4*)(bias + gq);

#pragma unroll
    for (int it = 0; it < 9; ++it) {
        int fi = it * 512 + tid;
        int b = fi / 288, r = fi - b * 288;
        int j = r >> 5, k4 = r & 31;
        unsigned byte = (unsigned)(b * 4352 + j * 256 + k4 * 8)
                      ^ (unsigned)((b & 7) << 4);
        uint4 u = __builtin_bit_cast(uint4, s1[it]);
        uint2 p; p.x = pkbf(u.x, u.y); p.y = pkbf(u.z, u.w);
        *(uint2*)(xs + byte) = p;
    }
#pragma unroll
    for (int it = 0; it < 8; ++it) {
        int fi = it * 512 + tid;
        int b = fi >> 8, r = fi & 255;
        int j = 9 + (r >> 5), k4 = r & 31;
        unsigned byte = (unsigned)(b * 4352 + j * 256 + k4 * 8)
                      ^ (unsigned)((b & 7) << 4);
        uint4 u = __builtin_bit_cast(uint4, s2[it]);
        uint2 p; p.x = pkbf(u.x, u.y); p.y = pkbf(u.z, u.w);
        *(uint2*)(xs + byte) = p;
    }
    __syncthreads();

    const unsigned rbase = (unsigned)(lrow * 4352);
    const unsigned swz   = (unsigned)((lrow & 7) << 4);
    float* ob = out + ((size_t)(b0 + lrow) * J) * F + gq;

    f32x4 acc[J];
#pragma unroll
    for (int i = 0; i < J; ++i) acc[i] = bias4;

    {   // pass B: off-diagonal (wf1 only live)
        bf16x8 wf[4];
#pragma unroll
        for (int ks = 0; ks < 4; ++ks)
            wf[ks] = __builtin_bit_cast(bf16x8,
                *(const uint4*)(WT + (size_t)(F * F) + (size_t)grow * F + ks * 32 + lq * 8));
#pragma unroll
        for (int j = 0; j < J; ++j) {
            f32x4 h1 = {0.f,0.f,0.f,0.f};
#pragma unroll
            for (int ks = 0; ks < 4; ++ks) {
                unsigned byte = (rbase + (unsigned)(j * 256 + ks * 64 + lq * 16)) ^ swz;
                bf16x8 xf = __builtin_bit_cast(bf16x8, *(const uint4*)(xs + byte));
                h1 = __builtin_amdgcn_mfma_f32_16x16x32_bf16(wf[ks], xf, h1, 0, 0, 0);
            }
            f32x4 mj  = *(const f32x4*)&Mw[j * F + gq];
            f32x4 mh1 = mj * h1;
#pragma unroll
            for (int i = 0; i < J; ++i)
                acc[i] = fma4(ws[i * J + j], mh1, acc[i]);
        }
    }
    {   // pass A: diagonal (wf0 only live)
        bf16x8 wf[4];
#pragma unroll
        for (int ks = 0; ks < 4; ++ks)
            wf[ks] = __builtin_bit_cast(bf16x8,
                *(const uint4*)(WT + (size_t)grow * F + ks * 32 + lq * 8));
#pragma unroll
        for (int j = 0; j < J; ++j) {
            f32x4 h0 = {0.f,0.f,0.f,0.f};
#pragma unroll
            for (int ks = 0; ks < 4; ++ks) {
                unsigned byte = (rbase + (unsigned)(j * 256 + ks * 64 + lq * 16)) ^ swz;
                bf16x8 xf = __builtin_bit_cast(bf16x8, *(const uint4*)(xs + byte));
                h0 = __builtin_amdgcn_mfma_f32_16x16x32_bf16(wf[ks], xf, h0, 0, 0, 0);
            }
            f32x4 dj = bf4(*(const ushort4*)(dMs + j * F + gq));
            acc[j] = __builtin_elementwise_fma(dj, h0, acc[j]);
            *(f32x4*)(ob + (size_t)j * F) = acc[j];
        }
    }
}

extern "C" void kernel_launch(void* const* d_in, const int* in_sizes, int n_in,
                              void* d_out, int out_size, void* d_ws, size_t ws_size,
                              hipStream_t stream) {
    const float* x    = (const float*)d_in[0];
    const float* W    = (const float*)d_in[1];
    const float* Mw   = (const float*)d_in[2];
    const float* adj  = (const float*)d_in[3];
    const float* adj2 = (const float*)d_in[4];
    const float* bias = (const float*)d_in[5];
    float* out = (float*)d_out;
    float* ws  = (float*)d_ws;   // needs >= 119808 B

    int Btot = in_sizes[0] / (J * F);        // 16384
    int tiles = Btot * J / 16;               // 17408 flat row-tiles
    prep<<<16, 256, 0, stream>>>(W, Mw, adj, adj2, bias, ws);
    mgcn_fast<<<tiles / 16, 256, 0, stream>>>(x, ws, ws, out);    // 1088 blocks
    mgcn_full<<<Btot / TB, 512, 0, stream>>>(x, Mw, bias, ws, out);
}